// Round 3
// baseline (877.428 us; speedup 1.0000x reference)
//
#include <hip/hip_runtime.h>
#include <stdint.h>

#define D_MODEL 768
#define BATCH   16
#define SEQ     2048
#define M_ROWS  (BATCH * SEQ)   // 32768
#define LN_EPS  1e-5f

#define CHUNKS  64
#define CLEN    (SEQ / CHUNKS)  // 32
#define PFA     8               // prefetch depth, scan phases 1/3
#define PFB     8               // prefetch depth, phase 2

typedef __attribute__((ext_vector_type(4))) float  f32x4;
typedef __attribute__((ext_vector_type(8))) __bf16 bf16x8;

__device__ __forceinline__ unsigned short f2bf(float f) {
    union { float f; uint32_t u; } v; v.f = f;
    uint32_t u = v.u;
    uint32_t r = (u + 0x7FFFu + ((u >> 16) & 1u)) >> 16;   // RNE
    return (unsigned short)r;
}
__device__ __forceinline__ float bf2f(unsigned short u) {
    union { uint32_t u; float f; } v; v.u = (uint32_t)u << 16; return v.f;
}

__device__ __forceinline__ void gload_lds16(const void* g, void* l) {
    __builtin_amdgcn_global_load_lds(
        (const __attribute__((address_space(1))) unsigned int*)g,
        (__attribute__((address_space(3))) unsigned int*)l,
        16, 0, 0);
}

// ---------------- Kernel 1: convert x -> bf16, fused decay GEMV ----------------
__global__ __launch_bounds__(256) void k_conv_decay(
    const float* __restrict__ x, const float* __restrict__ Wd,
    const float* __restrict__ bd, unsigned short* __restrict__ xb,
    float* __restrict__ decay)
{
    int row = blockIdx.x;
    int i   = threadIdx.x;
    const float* xr = x + (size_t)row * D_MODEL;
    float v0 = xr[i], v1 = xr[i + 256], v2 = xr[i + 512];
    unsigned short* xbr = xb + (size_t)row * D_MODEL;
    xbr[i] = f2bf(v0); xbr[i + 256] = f2bf(v1); xbr[i + 512] = f2bf(v2);

    float part = v0 * Wd[i] + v1 * Wd[i + 256] + v2 * Wd[i + 512];
    #pragma unroll
    for (int off = 32; off; off >>= 1) part += __shfl_down(part, off);
    __shared__ float wsum[4];
    int wid = i >> 6, lane = i & 63;
    if (lane == 0) wsum[wid] = part;
    __syncthreads();
    if (i == 0) {
        float s = wsum[0] + wsum[1] + wsum[2] + wsum[3] + bd[0];
        decay[row] = 1.f / (1.f + __expf(-s));
    }
}

// ---------------- Kernel 2: convert both weight matrices to bf16 (contiguous dest) ----------------
__global__ __launch_bounds__(256) void k_conv_w(
    const float* __restrict__ Wb, const float* __restrict__ Wi,
    unsigned short* __restrict__ Wdst)   // (1536,768): rows 0..767 = W_biv, 768..1535 = W_in
{
    const int NW = D_MODEL * D_MODEL;          // 589824
    int g = blockIdx.x * 256 + threadIdx.x;
    int base = g * 4;
    unsigned short* dst = Wdst + base;
    const float* src;
    if (base < NW) { src = Wb + base; }
    else           { src = Wi + (base - NW); }
    float4 v = *(const float4*)src;
    ushort4 o;
    o.x = f2bf(v.x); o.y = f2bf(v.y); o.z = f2bf(v.z); o.w = f2bf(v.w);
    *(ushort4*)dst = o;
}

// ---------------- Kernel 3: fused bf16 MFMA GEMM, C(M,1536) = A(M,768) * W(1536,768)^T + bias ---
// bf16 outputs split into biv (cols 0..767) and inj (cols 768..1535).
#define BM 128
#define BN 128
#define NBX 12   // 1536/BN

__global__ __launch_bounds__(256) void k_gemm_fused(
    const unsigned short* __restrict__ A,    // (M,768) bf16
    const unsigned short* __restrict__ Bw,   // (1536,768) bf16
    const float* __restrict__ bias_biv, const float* __restrict__ bias_in,
    unsigned short* __restrict__ bivb, unsigned short* __restrict__ injb)
{
    const int K = D_MODEL;
    __shared__ unsigned short As[BM * 32];  // 8 KiB
    __shared__ unsigned short Bs[BN * 32];  // 8 KiB

    // XCD-chunked swizzle: 3072 blocks, 384 per XCD, contiguous tile ranges per XCD
    int id  = blockIdx.x;
    int swz = (id & 7) * (NBX * (M_ROWS / BM) / 8) + (id >> 3);
    int bxc = swz % NBX, byr = swz / NBX;
    int m0 = byr * BM, n0 = bxc * BN;

    int tid  = threadIdx.x;
    int wave = tid >> 6, lane = tid & 63;
    int wm = wave >> 1, wn = wave & 1;      // 2x2 wave grid, 64x64 per wave

    f32x4 acc[4][4] = {};

    for (int k0 = 0; k0 < K; k0 += 32) {
        // stage A,B tiles; k-slot XOR-swizzled on the GLOBAL side (LDS dest linear)
        #pragma unroll
        for (int hh = 0; hh < 2; ++hh) {
            int c  = wave * 128 + hh * 64 + lane;
            int r  = c >> 2;
            int sl = (c & 3) ^ ((r >> 1) & 3);
            gload_lds16(A  + (size_t)(m0 + r) * K + k0 + sl * 8, (char*)As + c * 16);
            gload_lds16(Bw + (size_t)(n0 + r) * K + k0 + sl * 8, (char*)Bs + c * 16);
        }
        __syncthreads();

        bf16x8 af[4], bfr[4];
        int kq = lane >> 4;          // k-slot 0..3
        int rl = lane & 15;
        #pragma unroll
        for (int i = 0; i < 4; ++i) {
            int ra = wm * 64 + i * 16 + rl;
            int ca = kq ^ ((ra >> 1) & 3);
            af[i]  = *reinterpret_cast<const bf16x8*>((const char*)As + ra * 64 + ca * 16);
            int rb = wn * 64 + i * 16 + rl;
            int cb = kq ^ ((rb >> 1) & 3);
            bfr[i] = *reinterpret_cast<const bf16x8*>((const char*)Bs + rb * 64 + cb * 16);
        }
        #pragma unroll
        for (int i = 0; i < 4; ++i)
            #pragma unroll
            for (int j = 0; j < 4; ++j)
                acc[i][j] = __builtin_amdgcn_mfma_f32_16x16x32_bf16(af[i], bfr[j], acc[i][j], 0, 0, 0);
        __syncthreads();
    }

    // epilogue: C/D layout col=lane&15, row=(lane>>4)*4+reg; convert to bf16
    unsigned short* Cout; const float* bias; int nloc;
    if (n0 < D_MODEL) { Cout = bivb; bias = bias_biv; nloc = n0; }
    else              { Cout = injb; bias = bias_in;  nloc = n0 - D_MODEL; }
    int cl = lane & 15;
    int rg = (lane >> 4) * 4;
    #pragma unroll
    for (int j = 0; j < 4; ++j) {
        int col = nloc + wn * 64 + j * 16 + cl;
        float bs = bias[col];
        #pragma unroll
        for (int i = 0; i < 4; ++i) {
            int rowb = m0 + wm * 64 + i * 16 + rg;
            #pragma unroll
            for (int r = 0; r < 4; ++r)
                Cout[(size_t)(rowb + r) * D_MODEL + col] = f2bf(acc[i][j][r] + bs);
        }
    }
}

// ---------------- Scan phase 1: per-(chain,chunk) operator compose only ----------------
// thread gid -> j = gid&255, c = (gid>>8)&63, b = gid>>14
__global__ __launch_bounds__(256, 4) void k_scan_p1(
    const unsigned short* __restrict__ bivb, const unsigned short* __restrict__ injb,
    const float* __restrict__ decay,
    float* __restrict__ ops)          // per (b,c,j): {Qw,Qx,Qy,Qz,S,bx,by,bz}
{
    int gid = blockIdx.x * 256 + threadIdx.x;
    int j = gid & 255;
    int c = (gid >> 8) & (CHUNKS - 1);
    int b = gid >> 14;
    size_t rowbase = ((size_t)b * SEQ + c * CLEN) * D_MODEL + (size_t)j * 3;
    const unsigned short* bv = bivb + rowbase;
    const unsigned short* ij = injb + rowbase;
    const float* dk = decay + b * SEQ + c * CLEN;

    float pbx[PFA], pby[PFA], pbz[PFA], pix[PFA], piy[PFA], piz[PFA], pd[PFA];
    #pragma unroll
    for (int p = 0; p < PFA; ++p) {
        size_t o = (size_t)p * D_MODEL;
        pbx[p] = bf2f(bv[o]); pby[p] = bf2f(bv[o + 1]); pbz[p] = bf2f(bv[o + 2]);
        pix[p] = bf2f(ij[o]); piy[p] = bf2f(ij[o + 1]); piz[p] = bf2f(ij[o + 2]);
        pd[p]  = dk[p];
    }

    float hx = 0.f, hy = 0.f, hz = 0.f;
    float Qw = 1.f, Qx = 0.f, Qy = 0.f, Qz = 0.f, S = 1.f;
    for (int t0 = 0; t0 < CLEN; t0 += PFA) {
        #pragma unroll
        for (int p = 0; p < PFA; ++p) {
            int t = t0 + p;
            float bx = pbx[p], by = pby[p], bz = pbz[p];
            float ix = pix[p], iy = piy[p], iz = piz[p];
            float d  = pd[p];
            int tn = t + PFA;
            if (tn < CLEN) {
                size_t o = (size_t)tn * D_MODEL;
                pbx[p] = bf2f(bv[o]); pby[p] = bf2f(bv[o + 1]); pbz[p] = bf2f(bv[o + 2]);
                pix[p] = bf2f(ij[o]); piy[p] = bf2f(ij[o + 1]); piz[p] = bf2f(ij[o + 2]);
                pd[p]  = dk[tn];
            }
            float n2   = bx * bx + by * by + bz * bz;
            float nrm  = fmaxf(__builtin_sqrtf(n2), 1e-8f);
            float half = 0.5f * nrm;
            float w = __cosf(half);
            float s = __sinf(half) / nrm;
            float qx = s * bz, qy = -s * by, qz = s * bx;   // reversed mapping
            float tx = 2.f * (qy * hz - qz * hy);
            float ty = 2.f * (qz * hx - qx * hz);
            float tz = 2.f * (qx * hy - qy * hx);
            float rx = hx + w * tx + (qy * tz - qz * ty);
            float ry = hy + w * ty + (qz * tx - qx * tz);
            float rz = hz + w * tz + (qx * ty - qy * tx);
            hx = fmaf(d, rx, ix);
            hy = fmaf(d, ry, iy);
            hz = fmaf(d, rz, iz);
            // compose total operator: Q <- q_step (x) Q ; S <- d*S
            float nQw = w * Qw - qx * Qx - qy * Qy - qz * Qz;
            float nQx = w * Qx + Qw * qx + (qy * Qz - qz * Qy);
            float nQy = w * Qy + Qw * qy + (qz * Qx - qx * Qz);
            float nQz = w * Qz + Qw * qz + (qx * Qy - qy * Qx);
            Qw = nQw; Qx = nQx; Qy = nQy; Qz = nQz;
            S *= d;
        }
    }
    float* op = ops + ((size_t)(b * CHUNKS + c) * 256 + j) * 8;
    f32x4 o0 = {Qw, Qx, Qy, Qz};
    f32x4 o1 = {S, hx, hy, hz};
    *(f32x4*)op = o0;
    *(f32x4*)(op + 4) = o1;
}

// ---------------- Scan phase 2: sequential fold of 64 chunk operators per chain ----------------
__global__ __launch_bounds__(64) void k_scan_p2(
    const float* __restrict__ ops, float* __restrict__ hs)
{
    int gid = blockIdx.x * 64 + threadIdx.x;   // 0..4095
    int j = gid & 255, b = gid >> 8;

    float q0[PFB], q1[PFB], q2[PFB], q3[PFB], sc[PFB], o0[PFB], o1[PFB], o2[PFB];
    #pragma unroll
    for (int p = 0; p < PFB; ++p) {
        const float* op = ops + ((size_t)(b * CHUNKS + p) * 256 + j) * 8;
        f32x4 a = *(const f32x4*)op, bb = *(const f32x4*)(op + 4);
        q0[p] = a[0]; q1[p] = a[1]; q2[p] = a[2]; q3[p] = a[3];
        sc[p] = bb[0]; o0[p] = bb[1]; o1[p] = bb[2]; o2[p] = bb[3];
    }
    float hx = 0.f, hy = 0.f, hz = 0.f;
    for (int c0 = 0; c0 < CHUNKS; c0 += PFB) {
        #pragma unroll
        for (int p = 0; p < PFB; ++p) {
            int c = c0 + p;
            float* h = hs + ((size_t)(b * CHUNKS + c) * 256 + j) * 3;
            h[0] = hx; h[1] = hy; h[2] = hz;     // h at entry of chunk c
            float w = q0[p], qx = q1[p], qy = q2[p], qz = q3[p];
            float s = sc[p], bx = o0[p], by = o1[p], bz = o2[p];
            int cn = c + PFB;
            if (cn < CHUNKS) {
                const float* op = ops + ((size_t)(b * CHUNKS + cn) * 256 + j) * 8;
                f32x4 a = *(const f32x4*)op, bb = *(const f32x4*)(op + 4);
                q0[p] = a[0]; q1[p] = a[1]; q2[p] = a[2]; q3[p] = a[3];
                sc[p] = bb[0]; o0[p] = bb[1]; o1[p] = bb[2]; o2[p] = bb[3];
            }
            float tx = 2.f * (qy * hz - qz * hy);
            float ty = 2.f * (qz * hx - qx * hz);
            float tz = 2.f * (qx * hy - qy * hx);
            float rx = hx + w * tx + (qy * tz - qz * ty);
            float ry = hy + w * ty + (qz * tx - qx * tz);
            float rz = hz + w * tz + (qx * ty - qy * tx);
            hx = fmaf(s, rx, bx);
            hy = fmaf(s, ry, by);
            hz = fmaf(s, rz, bz);
        }
    }
}

// ---------------- Scan phase 3: full chunk scan from h_start + fused LayerNorm + residual ----
// block = (b, c): b = blockIdx.x >> 6, c = blockIdx.x & 63; thread = chain j
__global__ __launch_bounds__(256, 4) void k_scan_p3(
    const unsigned short* __restrict__ bivb, const unsigned short* __restrict__ injb,
    const float* __restrict__ decay, const float* __restrict__ hs,
    const float* __restrict__ x, const float* __restrict__ gamma,
    const float* __restrict__ beta, float* __restrict__ out)
{
    int blk = blockIdx.x;
    int c = blk & (CHUNKS - 1);
    int b = blk >> 6;
    int j = threadIdx.x;
    size_t rowbase = ((size_t)b * SEQ + c * CLEN) * D_MODEL + (size_t)j * 3;
    const unsigned short* bv = bivb + rowbase;
    const unsigned short* ij = injb + rowbase;
    const float*          xr = x    + rowbase;
    float*                po = out  + rowbase;
    const float* dk = decay + b * SEQ + c * CLEN;
    const float* h0 = hs + ((size_t)(b * CHUNKS + c) * 256 + j) * 3;
    float hx = h0[0], hy = h0[1], hz = h0[2];

    float g0 = gamma[j * 3], g1 = gamma[j * 3 + 1], g2 = gamma[j * 3 + 2];
    float e0 = beta[j * 3],  e1 = beta[j * 3 + 1],  e2 = beta[j * 3 + 2];

    float pbx[PFA], pby[PFA], pbz[PFA], pix[PFA], piy[PFA], piz[PFA], pd[PFA];
    float pxx[PFA], pxy[PFA], pxz[PFA];
    #pragma unroll
    for (int p = 0; p < PFA; ++p) {
        size_t o = (size_t)p * D_MODEL;
        pbx[p] = bf2f(bv[o]); pby[p] = bf2f(bv[o + 1]); pbz[p] = bf2f(bv[o + 2]);
        pix[p] = bf2f(ij[o]); piy[p] = bf2f(ij[o + 1]); piz[p] = bf2f(ij[o + 2]);
        pxx[p] = xr[o]; pxy[p] = xr[o + 1]; pxz[p] = xr[o + 2];
        pd[p]  = dk[p];
    }

    __shared__ float sb[8];
    __shared__ float mv[2];
    int wid = j >> 6, lane = j & 63;

    for (int t0 = 0; t0 < CLEN; t0 += PFA) {
        #pragma unroll
        for (int p = 0; p < PFA; ++p) {
            int t = t0 + p;
            float bx = pbx[p], by = pby[p], bz = pbz[p];
            float ix = pix[p], iy = piy[p], iz = piz[p];
            float rxx = pxx[p], rxy = pxy[p], rxz = pxz[p];
            float d  = pd[p];
            int tn = t + PFA;
            if (tn < CLEN) {
                size_t o = (size_t)tn * D_MODEL;
                pbx[p] = bf2f(bv[o]); pby[p] = bf2f(bv[o + 1]); pbz[p] = bf2f(bv[o + 2]);
                pix[p] = bf2f(ij[o]); piy[p] = bf2f(ij[o + 1]); piz[p] = bf2f(ij[o + 2]);
                pxx[p] = xr[o]; pxy[p] = xr[o + 1]; pxz[p] = xr[o + 2];
                pd[p]  = dk[tn];
            }
            float n2   = bx * bx + by * by + bz * bz;
            float nrm  = fmaxf(__builtin_sqrtf(n2), 1e-8f);
            float half = 0.5f * nrm;
            float w = __cosf(half);
            float s = __sinf(half) / nrm;
            float qx = s * bz, qy = -s * by, qz = s * bx;
            float tx = 2.f * (qy * hz - qz * hy);
            float ty = 2.f * (qz * hx - qx * hz);
            float tz = 2.f * (qx * hy - qy * hx);
            float rx = hx + w * tx + (qy * tz - qz * ty);
            float ry = hy + w * ty + (qz * tx - qx * tz);
            float rz = hz + w * tz + (qx * ty - qy * tx);
            hx = fmaf(d, rx, ix);
            hy = fmaf(d, ry, iy);
            hz = fmaf(d, rz, iz);

            // fused LayerNorm over the 768-row (256 threads x 3) + residual
            float sp = hx + hy + hz;
            float qp = hx * hx + hy * hy + hz * hz;
            #pragma unroll
            for (int off = 32; off; off >>= 1) {
                sp += __shfl_down(sp, off);
                qp += __shfl_down(qp, off);
            }
            if (lane == 0) { sb[wid] = sp; sb[wid + 4] = qp; }
            __syncthreads();
            if (j == 0) {
                float Ssum = sb[0] + sb[1] + sb[2] + sb[3];
                float Qsum = sb[4] + sb[5] + sb[6] + sb[7];
                float mean = Ssum * (1.f / 768.f);
                float var  = Qsum * (1.f / 768.f) - mean * mean;
                mv[0] = mean; mv[1] = rsqrtf(var + LN_EPS);
            }
            __syncthreads();
            float mean = mv[0], rstd = mv[1];
            float* o2 = po + (size_t)t * D_MODEL;
            o2[0] = (hx - mean) * rstd * g0 + e0 + rxx;
            o2[1] = (hy - mean) * rstd * g1 + e1 + rxy;
            o2[2] = (hz - mean) * rstd * g2 + e2 + rxz;
        }
    }
}

extern "C" void kernel_launch(void* const* d_in, const int* in_sizes, int n_in,
                              void* d_out, int out_size, void* d_ws, size_t ws_size,
                              hipStream_t stream) {
    const float* x     = (const float*)d_in[0];
    const float* W_biv = (const float*)d_in[1];
    const float* b_biv = (const float*)d_in[2];
    const float* W_dec = (const float*)d_in[3];
    const float* b_dec = (const float*)d_in[4];
    const float* W_in  = (const float*)d_in[5];
    const float* b_in  = (const float*)d_in[6];
    const float* gamma = (const float*)d_in[7];
    const float* beta  = (const float*)d_in[8];
    float* out = (float*)d_out;

    // workspace layout (153.5 MB)
    char* ws = (char*)d_ws;
    unsigned short* xb    = (unsigned short*)(ws);               // 50,331,648 B (dead after GEMM)
    unsigned short* Wcat  = (unsigned short*)(ws + 50331648);    //  2,359,296 B (1536x768 bf16)
    float*          decay = (float*)         (ws + 52690944);    //    131,072 B
    unsigned short* bivb  = (unsigned short*)(ws + 52822016);    // 50,331,648 B (bf16)
    unsigned short* injb  = (unsigned short*)(ws + 103153664);   // 50,331,648 B (bf16)
    // scan scratch reuses the xb region (dead after GEMM)
    float*          ops   = (float*)(ws);                        //  8,388,608 B
    float*          hs    = (float*)(ws + 8388608);              //  3,145,728 B

    (void)in_sizes; (void)n_in; (void)out_size; (void)ws_size;

    k_conv_decay<<<M_ROWS, 256, 0, stream>>>(x, W_dec, b_dec, xb, decay);
    k_conv_w    <<<1152,   256, 0, stream>>>(W_biv, W_in, Wcat);
    k_gemm_fused<<<NBX * (M_ROWS / BM), 256, 0, stream>>>(xb, Wcat, b_biv, b_in, bivb, injb);
    k_scan_p1   <<<1024, 256, 0, stream>>>(bivb, injb, decay, ops);
    k_scan_p2   <<<64,   64,  0, stream>>>(ops, hs);
    k_scan_p3   <<<1024, 256, 0, stream>>>(bivb, injb, decay, hs, x, gamma, beta, out);
}

// Round 4
// 260.817 us; speedup vs baseline: 3.3642x; 3.3642x over previous
//
#include <hip/hip_runtime.h>
#include <stdint.h>

#define D_MODEL 768
#define BATCH   16
#define SEQ     2048
#define M_ROWS  (BATCH * SEQ)   // 32768
#define LN_EPS  1e-5f

#define CHUNKS  64
#define CLEN    (SEQ / CHUNKS)  // 32
#define PFA     4               // prefetch depth, scan phases 1/3 (8 spilled at VGPR caps)
#define PFB     8               // prefetch depth, phase 2

typedef __attribute__((ext_vector_type(4))) float  f32x4;
typedef __attribute__((ext_vector_type(8))) __bf16 bf16x8;

__device__ __forceinline__ unsigned short f2bf(float f) {
    union { float f; uint32_t u; } v; v.f = f;
    uint32_t u = v.u;
    uint32_t r = (u + 0x7FFFu + ((u >> 16) & 1u)) >> 16;   // RNE
    return (unsigned short)r;
}
__device__ __forceinline__ float bf2f(unsigned short u) {
    union { uint32_t u; float f; } v; v.u = (uint32_t)u << 16; return v.f;
}

__device__ __forceinline__ void gload_lds16(const void* g, void* l) {
    __builtin_amdgcn_global_load_lds(
        (const __attribute__((address_space(1))) unsigned int*)g,
        (__attribute__((address_space(3))) unsigned int*)l,
        16, 0, 0);
}

// ---------------- Kernel 1: convert x -> bf16, fused decay GEMV ----------------
__global__ __launch_bounds__(256) void k_conv_decay(
    const float* __restrict__ x, const float* __restrict__ Wd,
    const float* __restrict__ bd, unsigned short* __restrict__ xb,
    float* __restrict__ decay)
{
    int row = blockIdx.x;
    int i   = threadIdx.x;
    const float* xr = x + (size_t)row * D_MODEL;
    float v0 = xr[i], v1 = xr[i + 256], v2 = xr[i + 512];
    unsigned short* xbr = xb + (size_t)row * D_MODEL;
    xbr[i] = f2bf(v0); xbr[i + 256] = f2bf(v1); xbr[i + 512] = f2bf(v2);

    float part = v0 * Wd[i] + v1 * Wd[i + 256] + v2 * Wd[i + 512];
    #pragma unroll
    for (int off = 32; off; off >>= 1) part += __shfl_down(part, off);
    __shared__ float wsum[4];
    int wid = i >> 6, lane = i & 63;
    if (lane == 0) wsum[wid] = part;
    __syncthreads();
    if (i == 0) {
        float s = wsum[0] + wsum[1] + wsum[2] + wsum[3] + bd[0];
        decay[row] = 1.f / (1.f + __expf(-s));
    }
}

// ---------------- Kernel 2: convert both weight matrices to bf16 (contiguous dest) ----------------
__global__ __launch_bounds__(256) void k_conv_w(
    const float* __restrict__ Wb, const float* __restrict__ Wi,
    unsigned short* __restrict__ Wdst)   // (1536,768): rows 0..767 = W_biv, 768..1535 = W_in
{
    const int NW = D_MODEL * D_MODEL;          // 589824
    int g = blockIdx.x * 256 + threadIdx.x;
    int base = g * 4;
    unsigned short* dst = Wdst + base;
    const float* src;
    if (base < NW) { src = Wb + base; }
    else           { src = Wi + (base - NW); }
    float4 v = *(const float4*)src;
    ushort4 o;
    o.x = f2bf(v.x); o.y = f2bf(v.y); o.z = f2bf(v.z); o.w = f2bf(v.w);
    *(ushort4*)dst = o;
}

// ---------------- Kernel 3: fused bf16 MFMA GEMM, C(M,1536) = A(M,768) * W(1536,768)^T + bias ---
#define BM 128
#define BN 128
#define NBX 12   // 1536/BN

__global__ __launch_bounds__(256) void k_gemm_fused(
    const unsigned short* __restrict__ A,    // (M,768) bf16
    const unsigned short* __restrict__ Bw,   // (1536,768) bf16
    const float* __restrict__ bias_biv, const float* __restrict__ bias_in,
    unsigned short* __restrict__ bivb, unsigned short* __restrict__ injb)
{
    const int K = D_MODEL;
    __shared__ unsigned short As[BM * 32];  // 8 KiB
    __shared__ unsigned short Bs[BN * 32];  // 8 KiB

    // XCD-chunked swizzle: 3072 blocks, 384 per XCD, contiguous tile ranges per XCD
    int id  = blockIdx.x;
    int swz = (id & 7) * (NBX * (M_ROWS / BM) / 8) + (id >> 3);
    int bxc = swz % NBX, byr = swz / NBX;
    int m0 = byr * BM, n0 = bxc * BN;

    int tid  = threadIdx.x;
    int wave = tid >> 6, lane = tid & 63;
    int wm = wave >> 1, wn = wave & 1;      // 2x2 wave grid, 64x64 per wave

    f32x4 acc[4][4] = {};

    for (int k0 = 0; k0 < K; k0 += 32) {
        // stage A,B tiles; k-slot XOR-swizzled on the GLOBAL side (LDS dest linear)
        #pragma unroll
        for (int hh = 0; hh < 2; ++hh) {
            int c  = wave * 128 + hh * 64 + lane;
            int r  = c >> 2;
            int sl = (c & 3) ^ ((r >> 1) & 3);
            gload_lds16(A  + (size_t)(m0 + r) * K + k0 + sl * 8, (char*)As + c * 16);
            gload_lds16(Bw + (size_t)(n0 + r) * K + k0 + sl * 8, (char*)Bs + c * 16);
        }
        __syncthreads();

        bf16x8 af[4], bfr[4];
        int kq = lane >> 4;          // k-slot 0..3
        int rl = lane & 15;
        #pragma unroll
        for (int i = 0; i < 4; ++i) {
            int ra = wm * 64 + i * 16 + rl;
            int ca = kq ^ ((ra >> 1) & 3);
            af[i]  = *reinterpret_cast<const bf16x8*>((const char*)As + ra * 64 + ca * 16);
            int rb = wn * 64 + i * 16 + rl;
            int cb = kq ^ ((rb >> 1) & 3);
            bfr[i] = *reinterpret_cast<const bf16x8*>((const char*)Bs + rb * 64 + cb * 16);
        }
        #pragma unroll
        for (int i = 0; i < 4; ++i)
            #pragma unroll
            for (int j = 0; j < 4; ++j)
                acc[i][j] = __builtin_amdgcn_mfma_f32_16x16x32_bf16(af[i], bfr[j], acc[i][j], 0, 0, 0);
        __syncthreads();
    }

    // epilogue: C/D layout col=lane&15, row=(lane>>4)*4+reg; convert to bf16
    unsigned short* Cout; const float* bias; int nloc;
    if (n0 < D_MODEL) { Cout = bivb; bias = bias_biv; nloc = n0; }
    else              { Cout = injb; bias = bias_in;  nloc = n0 - D_MODEL; }
    int cl = lane & 15;
    int rg = (lane >> 4) * 4;
    #pragma unroll
    for (int j = 0; j < 4; ++j) {
        int col = nloc + wn * 64 + j * 16 + cl;
        float bs = bias[col];
        #pragma unroll
        for (int i = 0; i < 4; ++i) {
            int rowb = m0 + wm * 64 + i * 16 + rg;
            #pragma unroll
            for (int r = 0; r < 4; ++r)
                Cout[(size_t)(rowb + r) * D_MODEL + col] = f2bf(acc[i][j][r] + bs);
        }
    }
}

// ---------------- Scan phase 1: per-(chain,chunk) operator compose only ----------------
// block -> (b, c) uniform; thread -> chain j. No min-waves bound (reg-heavy; avoid spill).
__global__ __launch_bounds__(256) void k_scan_p1(
    const unsigned short* __restrict__ bivb, const unsigned short* __restrict__ injb,
    const float* __restrict__ decay,
    float* __restrict__ ops)          // per (b,c,j): {Qw,Qx,Qy,Qz,S,bx,by,bz}
{
    int j = threadIdx.x;
    int c = blockIdx.x & (CHUNKS - 1);
    int b = blockIdx.x >> 6;
    size_t rowbase = ((size_t)b * SEQ + c * CLEN) * D_MODEL + (size_t)j * 3;
    const unsigned short* bv = bivb + rowbase;
    const unsigned short* ij = injb + rowbase;
    const float* dk = decay + b * SEQ + c * CLEN;   // wave-uniform -> scalar loads

    float pbx[PFA], pby[PFA], pbz[PFA], pix[PFA], piy[PFA], piz[PFA], pd[PFA];
    #pragma unroll
    for (int p = 0; p < PFA; ++p) {
        size_t o = (size_t)p * D_MODEL;
        pbx[p] = bf2f(bv[o]); pby[p] = bf2f(bv[o + 1]); pbz[p] = bf2f(bv[o + 2]);
        pix[p] = bf2f(ij[o]); piy[p] = bf2f(ij[o + 1]); piz[p] = bf2f(ij[o + 2]);
        pd[p]  = dk[p];
    }

    float hx = 0.f, hy = 0.f, hz = 0.f;
    float Qw = 1.f, Qx = 0.f, Qy = 0.f, Qz = 0.f, S = 1.f;
    for (int t0 = 0; t0 < CLEN; t0 += PFA) {
        #pragma unroll
        for (int p = 0; p < PFA; ++p) {
            int t = t0 + p;
            float bx = pbx[p], by = pby[p], bz = pbz[p];
            float ix = pix[p], iy = piy[p], iz = piz[p];
            float d  = pd[p];
            int tn = t + PFA;
            if (tn < CLEN) {
                size_t o = (size_t)tn * D_MODEL;
                pbx[p] = bf2f(bv[o]); pby[p] = bf2f(bv[o + 1]); pbz[p] = bf2f(bv[o + 2]);
                pix[p] = bf2f(ij[o]); piy[p] = bf2f(ij[o + 1]); piz[p] = bf2f(ij[o + 2]);
                pd[p]  = dk[tn];
            }
            float n2   = bx * bx + by * by + bz * bz;
            float nrm  = fmaxf(__builtin_sqrtf(n2), 1e-8f);
            float half = 0.5f * nrm;
            float w = __cosf(half);
            float s = __sinf(half) / nrm;
            float qx = s * bz, qy = -s * by, qz = s * bx;   // reversed mapping
            float tx = 2.f * (qy * hz - qz * hy);
            float ty = 2.f * (qz * hx - qx * hz);
            float tz = 2.f * (qx * hy - qy * hx);
            float rx = hx + w * tx + (qy * tz - qz * ty);
            float ry = hy + w * ty + (qz * tx - qx * tz);
            float rz = hz + w * tz + (qx * ty - qy * tx);
            hx = fmaf(d, rx, ix);
            hy = fmaf(d, ry, iy);
            hz = fmaf(d, rz, iz);
            // compose total operator: Q <- q_step (x) Q ; S <- d*S
            float nQw = w * Qw - qx * Qx - qy * Qy - qz * Qz;
            float nQx = w * Qx + Qw * qx + (qy * Qz - qz * Qy);
            float nQy = w * Qy + Qw * qy + (qz * Qx - qx * Qz);
            float nQz = w * Qz + Qw * qz + (qx * Qy - qy * Qx);
            Qw = nQw; Qx = nQx; Qy = nQy; Qz = nQz;
            S *= d;
        }
    }
    float* op = ops + ((size_t)(b * CHUNKS + c) * 256 + j) * 8;
    f32x4 o0 = {Qw, Qx, Qy, Qz};
    f32x4 o1 = {S, hx, hy, hz};
    *(f32x4*)op = o0;
    *(f32x4*)(op + 4) = o1;
}

// ---------------- Scan phase 2: sequential fold of 64 chunk operators per chain ----------------
__global__ __launch_bounds__(64) void k_scan_p2(
    const float* __restrict__ ops, float* __restrict__ hs)
{
    int gid = blockIdx.x * 64 + threadIdx.x;   // 0..4095
    int j = gid & 255, b = gid >> 8;

    float q0[PFB], q1[PFB], q2[PFB], q3[PFB], sc[PFB], o0[PFB], o1[PFB], o2[PFB];
    #pragma unroll
    for (int p = 0; p < PFB; ++p) {
        const float* op = ops + ((size_t)(b * CHUNKS + p) * 256 + j) * 8;
        f32x4 a = *(const f32x4*)op, bb = *(const f32x4*)(op + 4);
        q0[p] = a[0]; q1[p] = a[1]; q2[p] = a[2]; q3[p] = a[3];
        sc[p] = bb[0]; o0[p] = bb[1]; o1[p] = bb[2]; o2[p] = bb[3];
    }
    float hx = 0.f, hy = 0.f, hz = 0.f;
    for (int c0 = 0; c0 < CHUNKS; c0 += PFB) {
        #pragma unroll
        for (int p = 0; p < PFB; ++p) {
            int c = c0 + p;
            float* h = hs + ((size_t)(b * CHUNKS + c) * 256 + j) * 3;
            h[0] = hx; h[1] = hy; h[2] = hz;     // h at entry of chunk c
            float w = q0[p], qx = q1[p], qy = q2[p], qz = q3[p];
            float s = sc[p], bx = o0[p], by = o1[p], bz = o2[p];
            int cn = c + PFB;
            if (cn < CHUNKS) {
                const float* op = ops + ((size_t)(b * CHUNKS + cn) * 256 + j) * 8;
                f32x4 a = *(const f32x4*)op, bb = *(const f32x4*)(op + 4);
                q0[p] = a[0]; q1[p] = a[1]; q2[p] = a[2]; q3[p] = a[3];
                sc[p] = bb[0]; o0[p] = bb[1]; o1[p] = bb[2]; o2[p] = bb[3];
            }
            float tx = 2.f * (qy * hz - qz * hy);
            float ty = 2.f * (qz * hx - qx * hz);
            float tz = 2.f * (qx * hy - qy * hx);
            float rx = hx + w * tx + (qy * tz - qz * ty);
            float ry = hy + w * ty + (qz * tx - qx * tz);
            float rz = hz + w * tz + (qx * ty - qy * tx);
            hx = fmaf(s, rx, bx);
            hy = fmaf(s, ry, by);
            hz = fmaf(s, rz, bz);
        }
    }
}

// ---------------- Scan phase 3: full chunk scan from h_start + fused LayerNorm + residual ----
__global__ __launch_bounds__(256) void k_scan_p3(
    const unsigned short* __restrict__ bivb, const unsigned short* __restrict__ injb,
    const float* __restrict__ decay, const float* __restrict__ hs,
    const float* __restrict__ x, const float* __restrict__ gamma,
    const float* __restrict__ beta, float* __restrict__ out)
{
    int blk = blockIdx.x;
    int c = blk & (CHUNKS - 1);
    int b = blk >> 6;
    int j = threadIdx.x;
    size_t rowbase = ((size_t)b * SEQ + c * CLEN) * D_MODEL + (size_t)j * 3;
    const unsigned short* bv = bivb + rowbase;
    const unsigned short* ij = injb + rowbase;
    const float*          xr = x    + rowbase;
    float*                po = out  + rowbase;
    const float* dk = decay + b * SEQ + c * CLEN;
    const float* h0 = hs + ((size_t)(b * CHUNKS + c) * 256 + j) * 3;
    float hx = h0[0], hy = h0[1], hz = h0[2];

    float g0 = gamma[j * 3], g1 = gamma[j * 3 + 1], g2 = gamma[j * 3 + 2];
    float e0 = beta[j * 3],  e1 = beta[j * 3 + 1],  e2 = beta[j * 3 + 2];

    float pbx[PFA], pby[PFA], pbz[PFA], pix[PFA], piy[PFA], piz[PFA], pd[PFA];
    float pxx[PFA], pxy[PFA], pxz[PFA];
    #pragma unroll
    for (int p = 0; p < PFA; ++p) {
        size_t o = (size_t)p * D_MODEL;
        pbx[p] = bf2f(bv[o]); pby[p] = bf2f(bv[o + 1]); pbz[p] = bf2f(bv[o + 2]);
        pix[p] = bf2f(ij[o]); piy[p] = bf2f(ij[o + 1]); piz[p] = bf2f(ij[o + 2]);
        pxx[p] = xr[o]; pxy[p] = xr[o + 1]; pxz[p] = xr[o + 2];
        pd[p]  = dk[p];
    }

    __shared__ float sb[8];
    __shared__ float mv[2];
    int wid = j >> 6, lane = j & 63;

    for (int t0 = 0; t0 < CLEN; t0 += PFA) {
        #pragma unroll
        for (int p = 0; p < PFA; ++p) {
            int t = t0 + p;
            float bx = pbx[p], by = pby[p], bz = pbz[p];
            float ix = pix[p], iy = piy[p], iz = piz[p];
            float rxx = pxx[p], rxy = pxy[p], rxz = pxz[p];
            float d  = pd[p];
            int tn = t + PFA;
            if (tn < CLEN) {
                size_t o = (size_t)tn * D_MODEL;
                pbx[p] = bf2f(bv[o]); pby[p] = bf2f(bv[o + 1]); pbz[p] = bf2f(bv[o + 2]);
                pix[p] = bf2f(ij[o]); piy[p] = bf2f(ij[o + 1]); piz[p] = bf2f(ij[o + 2]);
                pxx[p] = xr[o]; pxy[p] = xr[o + 1]; pxz[p] = xr[o + 2];
                pd[p]  = dk[tn];
            }
            float n2   = bx * bx + by * by + bz * bz;
            float nrm  = fmaxf(__builtin_sqrtf(n2), 1e-8f);
            float half = 0.5f * nrm;
            float w = __cosf(half);
            float s = __sinf(half) / nrm;
            float qx = s * bz, qy = -s * by, qz = s * bx;
            float tx = 2.f * (qy * hz - qz * hy);
            float ty = 2.f * (qz * hx - qx * hz);
            float tz = 2.f * (qx * hy - qy * hx);
            float rx = hx + w * tx + (qy * tz - qz * ty);
            float ry = hy + w * ty + (qz * tx - qx * tz);
            float rz = hz + w * tz + (qx * ty - qy * tx);
            hx = fmaf(d, rx, ix);
            hy = fmaf(d, ry, iy);
            hz = fmaf(d, rz, iz);

            // fused LayerNorm over the 768-row (256 threads x 3) + residual
            float sp = hx + hy + hz;
            float qp = hx * hx + hy * hy + hz * hz;
            #pragma unroll
            for (int off = 32; off; off >>= 1) {
                sp += __shfl_down(sp, off);
                qp += __shfl_down(qp, off);
            }
            if (lane == 0) { sb[wid] = sp; sb[wid + 4] = qp; }
            __syncthreads();
            if (j == 0) {
                float Ssum = sb[0] + sb[1] + sb[2] + sb[3];
                float Qsum = sb[4] + sb[5] + sb[6] + sb[7];
                float mean = Ssum * (1.f / 768.f);
                float var  = Qsum * (1.f / 768.f) - mean * mean;
                mv[0] = mean; mv[1] = rsqrtf(var + LN_EPS);
            }
            __syncthreads();
            float mean = mv[0], rstd = mv[1];
            float* o2 = po + (size_t)t * D_MODEL;
            o2[0] = (hx - mean) * rstd * g0 + e0 + rxx;
            o2[1] = (hy - mean) * rstd * g1 + e1 + rxy;
            o2[2] = (hz - mean) * rstd * g2 + e2 + rxz;
        }
    }
}

extern "C" void kernel_launch(void* const* d_in, const int* in_sizes, int n_in,
                              void* d_out, int out_size, void* d_ws, size_t ws_size,
                              hipStream_t stream) {
    const float* x     = (const float*)d_in[0];
    const float* W_biv = (const float*)d_in[1];
    const float* b_biv = (const float*)d_in[2];
    const float* W_dec = (const float*)d_in[3];
    const float* b_dec = (const float*)d_in[4];
    const float* W_in  = (const float*)d_in[5];
    const float* b_in  = (const float*)d_in[6];
    const float* gamma = (const float*)d_in[7];
    const float* beta  = (const float*)d_in[8];
    float* out = (float*)d_out;

    // workspace layout (153.5 MB)
    char* ws = (char*)d_ws;
    unsigned short* xb    = (unsigned short*)(ws);               // 50,331,648 B (dead after GEMM)
    unsigned short* Wcat  = (unsigned short*)(ws + 50331648);    //  2,359,296 B (1536x768 bf16)
    float*          decay = (float*)         (ws + 52690944);    //    131,072 B
    unsigned short* bivb  = (unsigned short*)(ws + 52822016);    // 50,331,648 B (bf16)
    unsigned short* injb  = (unsigned short*)(ws + 103153664);   // 50,331,648 B (bf16)
    // scan scratch reuses the xb region (dead after GEMM)
    float*          ops   = (float*)(ws);                        //  8,388,608 B
    float*          hs    = (float*)(ws + 8388608);              //  3,145,728 B

    (void)in_sizes; (void)n_in; (void)out_size; (void)ws_size;

    k_conv_decay<<<M_ROWS, 256, 0, stream>>>(x, W_dec, b_dec, xb, decay);
    k_conv_w    <<<1152,   256, 0, stream>>>(W_biv, W_in, Wcat);
    k_gemm_fused<<<NBX * (M_ROWS / BM), 256, 0, stream>>>(xb, Wcat, b_biv, b_in, bivb, injb);
    k_scan_p1   <<<1024, 256, 0, stream>>>(bivb, injb, decay, ops);
    k_scan_p2   <<<64,   64,  0, stream>>>(ops, hs);
    k_scan_p3   <<<1024, 256, 0, stream>>>(bivb, injb, decay, hs, x, gamma, beta, out);
}